// Round 4
// baseline (143.451 us; speedup 1.0000x reference)
//
#include <hip/hip_runtime.h>

typedef _Float16 f16;
typedef _Float16 f16x4 __attribute__((ext_vector_type(4)));
typedef _Float16 f16x8 __attribute__((ext_vector_type(8)));
typedef float f32x4 __attribute__((ext_vector_type(4)));

#define L2E 1.44269504088896340736f

constexpr int D  = 512;
constexpr int S  = 1024;
constexpr int B  = 4;
constexpr int BS = B * S;   // 4096

// workspace layout (bytes); total ~18.9 MB
constexpr size_t OFF_WT   = 0;                               // 4 * 512*512 f16 (WqT,WkT,WvT,WoT)
constexpr size_t OFF_Q16  = OFF_WT  + 4ull * D * D * 2;
constexpr size_t OFF_K16  = OFF_Q16 + (size_t)BS * D * 2;
constexpr size_t OFF_VT   = OFF_K16 + (size_t)BS * D * 2;    // v, transposed: [b*512+n][S]
constexpr size_t OFF_AT   = OFF_VT  + (size_t)BS * D * 2;    // attention output f16 [BS][D]
constexpr size_t OFF_TAB  = OFF_AT  + (size_t)BS * D * 2;    // float [8][1032]
constexpr size_t OFF_COEF = OFF_TAB + 8ull * 1032 * 4;       // float c[8], d[8]; int flag[8]

// ---------------------------------------------------------------------------
// Kernel 1: weight transpose + f32->f16 convert.  WT[n][k] = (f16)W[k][n]
// ---------------------------------------------------------------------------
__global__ __launch_bounds__(256) void wtrans(const float* __restrict__ Wq, const float* __restrict__ Wk,
                                              const float* __restrict__ Wv, const float* __restrict__ Wo,
                                              f16* __restrict__ WT)
{
    __shared__ float tile[64][65];
    const int z = blockIdx.z;
    const float* __restrict__ W = (z == 0) ? Wq : (z == 1) ? Wk : (z == 2) ? Wv : Wo;
    f16* __restrict__ out = WT + (size_t)z * D * D;
    const int k0 = blockIdx.x * 64, n0 = blockIdx.y * 64;
    for (int i = threadIdx.x; i < 4096; i += 256) {
        int r = i >> 6, c = i & 63;
        tile[r][c] = W[(size_t)(k0 + r) * D + n0 + c];
    }
    __syncthreads();
    for (int i = threadIdx.x; i < 4096; i += 256) {
        int nn = i >> 6, kk = i & 63;
        out[(size_t)(n0 + nn) * D + k0 + kk] = (f16)tile[kk][nn];
    }
}

// ---------------------------------------------------------------------------
// Kernel 2: temporal-bias LUT + linearity detection (weights staged in LDS).
// ---------------------------------------------------------------------------
__global__ __launch_bounds__(1024) void build_table(const float* __restrict__ Wt1, const float* __restrict__ bt1,
                                                    const float* __restrict__ Wt2, const float* __restrict__ bt2,
                                                    float* __restrict__ tab, float* __restrict__ coef)
{
    __shared__ float w1s[32], b1s[32], w2s[256], b2s[8];
    __shared__ int dev[8];
    const int t = threadIdx.x;
    if (t < 32)               { w1s[t] = Wt1[t]; b1s[t] = bt1[t]; }
    if (t >= 64 && t < 320)   w2s[t - 64] = Wt2[t - 64];
    if (t >= 320 && t < 328)  b2s[t - 320] = bt2[t - 320];
    if (t < 8) dev[t] = 0;
    __syncthreads();

    float f0[8], f1[8];
#pragma unroll
    for (int hh = 0; hh < 8; ++hh) { f0[hh] = b2s[hh]; f1[hh] = b2s[hh]; }
#pragma unroll 4
    for (int j = 0; j < 32; ++j) {
        float w1 = w1s[j], b1 = b1s[j];
        float h0 = fmaxf(b1, 0.f);
        float h1 = fmaxf(w1 + b1, 0.f);
#pragma unroll
        for (int hh = 0; hh < 8; ++hh) {
            float w2 = w2s[j * 8 + hh];
            f0[hh] += h0 * w2;
            f1[hh] += h1 * w2;
        }
    }

    for (int idx = t; idx <= 1024; idx += 1024) {
        float tdv = (float)idx * (1.0f / 1024.0f);
        float acc[8];
#pragma unroll
        for (int hh = 0; hh < 8; ++hh) acc[hh] = b2s[hh];
#pragma unroll 4
        for (int j = 0; j < 32; ++j) {
            float hv = fmaxf(fmaf(tdv, w1s[j], b1s[j]), 0.f);
#pragma unroll
            for (int hh = 0; hh < 8; ++hh) acc[hh] += hv * w2s[j * 8 + hh];
        }
#pragma unroll
        for (int hh = 0; hh < 8; ++hh) {
            float v = acc[hh] * L2E;
            tab[hh * 1032 + idx] = v;
            float linv = (f0[hh] + tdv * (f1[hh] - f0[hh])) * L2E;
            float dvv = fabsf(v - linv);
            atomicMax(&dev[hh], __float_as_int(dvv));
        }
    }
    __syncthreads();
    if (t == 0) {
#pragma unroll
        for (int hh = 0; hh < 8; ++hh) {
            coef[hh]     = (f1[hh] - f0[hh]) * L2E;
            coef[8 + hh] = f0[hh] * L2E;
            ((int*)coef)[16 + hh] = (__int_as_float(dev[hh]) < 1e-4f) ? 1 : 0;
        }
    }
}

// ---------------------------------------------------------------------------
// Kernel 3: fused q/k/v projection GEMM.  C = A(f32) @ W + b  -> f16.
// R3: 128x64 tile -> grid (32,8,3)=768 blocks (3/CU; was 384=1.5/CU).
// 4 waves (2x2 of 64x32), BK=32, double-buffered LDS.
// ---------------------------------------------------------------------------
__global__ __launch_bounds__(256) void proj_gemm(
    const float* __restrict__ Aq, const float* __restrict__ Ak, const float* __restrict__ Av,
    const f16* __restrict__ WT,
    const float* __restrict__ bq, const float* __restrict__ bk, const float* __restrict__ bv,
    f16* __restrict__ q16, f16* __restrict__ k16, f16* __restrict__ vT, float qscale)
{
    __shared__ f16 As[2][128][40];
    __shared__ f16 Bs[2][64][40];

    const int z = blockIdx.z;
    const float* __restrict__ A    = (z == 0) ? Aq : (z == 1) ? Ak : Av;
    const float* __restrict__ bias = (z == 0) ? bq : (z == 1) ? bk : bv;
    const f16* __restrict__ W      = WT + (size_t)z * D * D;
    const float scale = (z == 0) ? qscale : 1.0f;

    const int t = threadIdx.x;
    const int l = t & 63, w = t >> 6;
    const int i16 = l & 15, g = l >> 4;
    const int wm = w >> 1, wn = w & 1;
    const int m0 = blockIdx.x * 128, n0 = blockIdx.y * 64;

    f32x4 acc[4][2] = {};

    float4 ar[4];
    f16x8  br;
    const int arow = t >> 3, ac4 = t & 7;      // A stage: 4 rounds of 32 rows
    const int brow = t >> 2, bc8 = t & 3;      // B stage: 1 round

    auto load_stage = [&](int kt) {
        const int k0 = kt * 32;
#pragma unroll
        for (int r = 0; r < 4; ++r)
            ar[r] = *reinterpret_cast<const float4*>(A + (size_t)(m0 + arow + 32 * r) * D + k0 + ac4 * 4);
        br = *reinterpret_cast<const f16x8*>(W + (size_t)(n0 + brow) * D + k0 + bc8 * 8);
    };
    auto write_stage = [&](int buf) {
#pragma unroll
        for (int r = 0; r < 4; ++r) {
            f16x4 hv;
            hv[0] = (f16)ar[r].x; hv[1] = (f16)ar[r].y; hv[2] = (f16)ar[r].z; hv[3] = (f16)ar[r].w;
            *reinterpret_cast<f16x4*>(&As[buf][arow + 32 * r][ac4 * 4]) = hv;
        }
        *reinterpret_cast<f16x8*>(&Bs[buf][brow][bc8 * 8]) = br;
    };

    load_stage(0);
    write_stage(0);
    __syncthreads();

    for (int kt = 0; kt < 16; ++kt) {
        const int cur = kt & 1;
        if (kt < 15) load_stage(kt + 1);

        f16x8 af[4], bf[2];
#pragma unroll
        for (int i = 0; i < 4; ++i)
            af[i] = *reinterpret_cast<const f16x8*>(&As[cur][wm * 64 + i * 16 + i16][g * 8]);
#pragma unroll
        for (int j = 0; j < 2; ++j)
            bf[j] = *reinterpret_cast<const f16x8*>(&Bs[cur][wn * 32 + j * 16 + i16][g * 8]);
#pragma unroll
        for (int i = 0; i < 4; ++i)
#pragma unroll
            for (int j = 0; j < 2; ++j)
                acc[i][j] = __builtin_amdgcn_mfma_f32_16x16x32_f16(af[i], bf[j], acc[i][j], 0, 0, 0);

        if (kt < 15) write_stage(cur ^ 1);
        __syncthreads();
    }

    float bvv[2];
#pragma unroll
    for (int j = 0; j < 2; ++j) bvv[j] = bias[n0 + wn * 32 + j * 16 + i16];

    if (z < 2) {
        f16* __restrict__ out = (z == 0) ? q16 : k16;
#pragma unroll
        for (int i = 0; i < 4; ++i) {
#pragma unroll
            for (int j = 0; j < 2; ++j) {
                const int nn = n0 + wn * 32 + j * 16 + i16;
#pragma unroll
                for (int e = 0; e < 4; ++e) {
                    const int mr = m0 + wm * 64 + i * 16 + g * 4 + e;
                    out[(size_t)mr * D + nn] = (f16)((acc[i][j][e] + bvv[j]) * scale);
                }
            }
        }
    } else {
        // transposed store: vT[(b*512 + n)*1024 + j_in_seq]
#pragma unroll
        for (int i = 0; i < 4; ++i) {
            const int mr = m0 + wm * 64 + i * 16 + g * 4;  // 4 consecutive rows via e
            const int bb = mr >> 10, jj = mr & 1023;
#pragma unroll
            for (int j = 0; j < 2; ++j) {
                const int nn = n0 + wn * 32 + j * 16 + i16;
                f16x4 hv;
#pragma unroll
                for (int e = 0; e < 4; ++e) hv[e] = (f16)(acc[i][j][e] + bvv[j]);
                *reinterpret_cast<f16x4*>(vT + ((size_t)(bb * D + nn)) * S + jj) = hv;
            }
        }
    }
}

// ---------------------------------------------------------------------------
// Kernel 4: fused flash attention with temporal bias.
// R3: barrier-free.  1 wave (64 thr) per block, 16 q-rows/wave, 2048 blocks
// (8 blocks/CU).  K/V MFMA fragments read DIRECTLY from global (L2-resident;
// LDS staging only existed for cross-wave sharing, which forced lockstep
// barriers).  Explicit A/B register ping-pong prefetches K/V/td one full
// KV-tile ahead.  P relay via tiny per-wave LDS (only DS ops left).
// ---------------------------------------------------------------------------
__global__ __launch_bounds__(64, 2) void attn_kernel(
    const f16* __restrict__ q16, const f16* __restrict__ k16, const f16* __restrict__ vT,
    const float* __restrict__ td, const float* __restrict__ tabg, const float* __restrict__ coef,
    f16* __restrict__ out16)
{
    __shared__ f16 Ps[16][40];

    // bid = qt*32 + h*4 + b : XCD (bid&7) pins one batch b + one head-parity,
    // so each XCD's L2 sees ~1 MB of K/V slices.
    const int bid = blockIdx.x;
    const int b  = bid & 3;
    const int h  = (bid >> 2) & 7;
    const int qt = bid >> 5;                 // [0,64)

    const int l = threadIdx.x;
    const int i16 = l & 15, g = l >> 4;
    const int qrow = qt * 16 + i16;

    const float cH = coef[h], dH = coef[8 + h];
    const int lin = ((const int*)coef)[16 + h];
    const float* __restrict__ th = tabg + h * 1032;

    f16x8 qf[2];
#pragma unroll
    for (int kf = 0; kf < 2; ++kf)
        qf[kf] = *reinterpret_cast<const f16x8*>(
            q16 + (size_t)(b * S + qrow) * D + h * 64 + kf * 32 + g * 8);

    float mr = -1e30f, lr = 0.f;
    f32x4 o[4] = {};

    const f16* __restrict__ kbase = k16 + (size_t)b * S * D + h * 64 + g * 8;
    const f16* __restrict__ vbase = vT + (size_t)(b * D + h * 64 + i16) * S + g * 8;
    const float* __restrict__ tdrow = td + (size_t)(b * S + qrow) * S + g * 4;

    auto loadK = [&](f16x8* kr, int jt) {
#pragma unroll
        for (int fj = 0; fj < 2; ++fj) {
            const f16* p = kbase + (size_t)(jt * 32 + fj * 16 + i16) * D;
            kr[fj * 2 + 0] = *reinterpret_cast<const f16x8*>(p);
            kr[fj * 2 + 1] = *reinterpret_cast<const f16x8*>(p + 32);
        }
    };
    auto loadV = [&](f16x8* vr, int jt) {
#pragma unroll
        for (int fv = 0; fv < 4; ++fv)
            vr[fv] = *reinterpret_cast<const f16x8*>(vbase + (size_t)(fv * 16) * S + jt * 32);
    };
    auto loadT = [&](float4& t0, float4& t1, int jt) {
        t0 = *reinterpret_cast<const float4*>(tdrow + jt * 32);
        t1 = *reinterpret_cast<const float4*>(tdrow + jt * 32 + 16);
    };

    auto tile = [&](const f16x8* kr, const f16x8* vr, float4 t0, float4 t1) {
        // ---- S^T = K * Q^T ----
        f32x4 s[2];
#pragma unroll
        for (int fj = 0; fj < 2; ++fj) {
            f32x4 zz = {0.f, 0.f, 0.f, 0.f};
            zz = __builtin_amdgcn_mfma_f32_16x16x32_f16(kr[fj * 2 + 0], qf[0], zz, 0, 0, 0);
            s[fj] = __builtin_amdgcn_mfma_f32_16x16x32_f16(kr[fj * 2 + 1], qf[1], zz, 0, 0, 0);
        }

        // ---- bias + online softmax (per-lane q-row i16) ----
        float pvv[2][4];
        float tmax = -1e30f;
#pragma unroll
        for (int fj = 0; fj < 2; ++fj) {
            const float4 t4 = fj ? t1 : t0;
            float ta4[4] = {t4.x, t4.y, t4.z, t4.w};
#pragma unroll
            for (int e = 0; e < 4; ++e) {
                float u = ta4[e];
                float vsc;
                if (lin) {
                    vsc = fmaf(u, cH, s[fj][e] + dH);       // td in [0,1): no clamp
                } else {
                    float x = fminf(fmaxf(u, 0.f), 1.f) * 1024.f;
                    int ix = (int)x;
                    ix = (ix > 1023) ? 1023 : ix;
                    float fr = x - (float)ix;
                    float t0v = th[ix], t1v = th[ix + 1];
                    vsc = s[fj][e] + fmaf(fr, t1v - t0v, t0v);
                }
                pvv[fj][e] = vsc;
                tmax = fmaxf(tmax, vsc);
            }
        }
        tmax = fmaxf(tmax, __shfl_xor(tmax, 16));
        tmax = fmaxf(tmax, __shfl_xor(tmax, 32));
        if (__any(tmax > mr)) {                  // T13: skip rescale when max unchanged
            float mnew = fmaxf(mr, tmax);
            float alpha = exp2f(mr - mnew);
            mr = mnew;
            lr *= alpha;
#pragma unroll
            for (int fv = 0; fv < 4; ++fv) o[fv] *= alpha;
        }

        float rsum = 0.f;
        f16x4 pq[2];
#pragma unroll
        for (int fj = 0; fj < 2; ++fj)
#pragma unroll
            for (int e = 0; e < 4; ++e) {
                float p = exp2f(pvv[fj][e] - mr);
                rsum += p;
                pq[fj][e] = (f16)p;
            }
        rsum += __shfl_xor(rsum, 16);
        rsum += __shfl_xor(rsum, 32);
        lr += rsum;

        // P^T relay through per-wave LDS (same wave: no barrier)
        *reinterpret_cast<f16x4*>(&Ps[i16][g * 4])      = pq[0];
        *reinterpret_cast<f16x4*>(&Ps[i16][16 + g * 4]) = pq[1];
        f16x8 pb = *reinterpret_cast<const f16x8*>(&Ps[i16][g * 8]);

        // ---- out^T += V^T * P^T ----
#pragma unroll
        for (int fv = 0; fv < 4; ++fv)
            o[fv] = __builtin_amdgcn_mfma_f32_16x16x32_f16(vr[fv], pb, o[fv], 0, 0, 0);
    };

    f16x8 kA[4], vA[4], kB[4], vB[4];
    float4 tA0, tA1, tB0, tB1;

    loadK(kA, 0); loadV(vA, 0); loadT(tA0, tA1, 0);
    loadK(kB, 1); loadV(vB, 1); loadT(tB0, tB1, 1);

    for (int p = 0; p < 16; ++p) {
        tile(kA, vA, tA0, tA1);
        if (p < 15) { loadK(kA, 2 * p + 2); loadV(vA, 2 * p + 2); loadT(tA0, tA1, 2 * p + 2); }
        tile(kB, vB, tB0, tB1);
        if (p < 15) { loadK(kB, 2 * p + 3); loadV(vB, 2 * p + 3); loadT(tB0, tB1, 2 * p + 3); }
    }

    // epilogue: out[i][dv] = o^T / lsum
    const float rl = 1.f / lr;
#pragma unroll
    for (int fv = 0; fv < 4; ++fv) {
        f16x4 hv;
#pragma unroll
        for (int e = 0; e < 4; ++e) hv[e] = (f16)(o[fv][e] * rl);
        *reinterpret_cast<f16x4*>(
            out16 + (size_t)(b * S + qrow) * D + h * 64 + fv * 16 + g * 4) = hv;
    }
}

// ---------------------------------------------------------------------------
// Kernel 5: output projection.  out(f32) = attn16(f16) @ Wo + bo
// R3: 64x64 tile -> grid (64,8)=512 blocks (2/CU; was 128=0.5/CU).
// ---------------------------------------------------------------------------
__global__ __launch_bounds__(256) void final_gemm(const f16* __restrict__ A, const f16* __restrict__ WoT,
                                                  const float* __restrict__ bo, float* __restrict__ out)
{
    __shared__ f16 As[2][64][40];
    __shared__ f16 Bs[2][64][40];

    const int t = threadIdx.x;
    const int l = t & 63, w = t >> 6;
    const int i16 = l & 15, g = l >> 4;
    const int wm = w >> 1, wn = w & 1;
    const int m0 = blockIdx.x * 64, n0 = blockIdx.y * 64;

    f32x4 acc[2][2] = {};
    f16x8 ar, br;
    const int srow = t >> 2, sc8 = t & 3;

    auto load_stage = [&](int kt) {
        const int k0 = kt * 32;
        ar = *reinterpret_cast<const f16x8*>(A + (size_t)(m0 + srow) * D + k0 + sc8 * 8);
        br = *reinterpret_cast<const f16x8*>(WoT + (size_t)(n0 + srow) * D + k0 + sc8 * 8);
    };
    auto write_stage = [&](int buf) {
        *reinterpret_cast<f16x8*>(&As[buf][srow][sc8 * 8]) = ar;
        *reinterpret_cast<f16x8*>(&Bs[buf][srow][sc8 * 8]) = br;
    };

    load_stage(0);
    write_stage(0);
    __syncthreads();

    for (int kt = 0; kt < 16; ++kt) {
        const int cur = kt & 1;
        if (kt < 15) load_stage(kt + 1);

        f16x8 af[2], bf[2];
#pragma unroll
        for (int i = 0; i < 2; ++i)
            af[i] = *reinterpret_cast<const f16x8*>(&As[cur][wm * 32 + i * 16 + i16][g * 8]);
#pragma unroll
        for (int j = 0; j < 2; ++j)
            bf[j] = *reinterpret_cast<const f16x8*>(&Bs[cur][wn * 32 + j * 16 + i16][g * 8]);
#pragma unroll
        for (int i = 0; i < 2; ++i)
#pragma unroll
            for (int j = 0; j < 2; ++j)
                acc[i][j] = __builtin_amdgcn_mfma_f32_16x16x32_f16(af[i], bf[j], acc[i][j], 0, 0, 0);

        if (kt < 15) write_stage(cur ^ 1);
        __syncthreads();
    }

    float bvv[2];
#pragma unroll
    for (int j = 0; j < 2; ++j) bvv[j] = bo[n0 + wn * 32 + j * 16 + i16];

#pragma unroll
    for (int i = 0; i < 2; ++i) {
#pragma unroll
        for (int j = 0; j < 2; ++j) {
            const int nn = n0 + wn * 32 + j * 16 + i16;
#pragma unroll
            for (int e = 0; e < 4; ++e) {
                const int mr = m0 + wm * 32 + i * 16 + g * 4 + e;
                out[(size_t)mr * D + nn] = acc[i][j][e] + bvv[j];
            }
        }
    }
}

// ---------------------------------------------------------------------------
extern "C" void kernel_launch(void* const* d_in, const int* in_sizes, int n_in,
                              void* d_out, int out_size, void* d_ws, size_t ws_size,
                              hipStream_t stream)
{
    (void)in_sizes; (void)n_in; (void)out_size; (void)ws_size; // needs ~19 MB of ws

    const float* query = (const float*)d_in[0];
    const float* key_  = (const float*)d_in[1];
    const float* value = (const float*)d_in[2];
    const float* td    = (const float*)d_in[3];
    const float* Wq  = (const float*)d_in[4];  const float* bq  = (const float*)d_in[5];
    const float* Wk  = (const float*)d_in[6];  const float* bk  = (const float*)d_in[7];
    const float* Wv  = (const float*)d_in[8];  const float* bv  = (const float*)d_in[9];
    const float* Wo  = (const float*)d_in[10]; const float* bo  = (const float*)d_in[11];
    const float* Wt1 = (const float*)d_in[12]; const float* bt1 = (const float*)d_in[13];
    const float* Wt2 = (const float*)d_in[14]; const float* bt2 = (const float*)d_in[15];
    float* out = (float*)d_out;

    char* ws = (char*)d_ws;
    f16*   WT   = (f16*)(ws + OFF_WT);
    f16*   q16  = (f16*)(ws + OFF_Q16);
    f16*   k16  = (f16*)(ws + OFF_K16);
    f16*   vT   = (f16*)(ws + OFF_VT);
    f16*   at16 = (f16*)(ws + OFF_AT);
    float* tab  = (float*)(ws + OFF_TAB);
    float* coef = (float*)(ws + OFF_COEF);

    wtrans<<<dim3(8, 8, 4), 256, 0, stream>>>(Wq, Wk, Wv, Wo, WT);
    build_table<<<1, 1024, 0, stream>>>(Wt1, bt1, Wt2, bt2, tab, coef);
    proj_gemm<<<dim3(32, 8, 3), 256, 0, stream>>>(query, key_, value, WT, bq, bk, bv,
                                                  q16, k16, vT, 0.125f * L2E);
    attn_kernel<<<2048, 64, 0, stream>>>(q16, k16, vT, td, tab, coef, at16);
    final_gemm<<<dim3(64, 8), 256, 0, stream>>>(at16, WT + 3ull * (size_t)D * D, bo, out);
}

// Round 5
// 105.519 us; speedup vs baseline: 1.3595x; 1.3595x over previous
//
#include <hip/hip_runtime.h>

typedef _Float16 f16;
typedef _Float16 f16x4 __attribute__((ext_vector_type(4)));
typedef _Float16 f16x8 __attribute__((ext_vector_type(8)));
typedef float f32x4 __attribute__((ext_vector_type(4)));

#define L2E 1.44269504088896340736f

constexpr int D  = 512;
constexpr int S  = 1024;
constexpr int B  = 4;
constexpr int BS = B * S;   // 4096

// workspace layout (bytes); total ~18.9 MB
constexpr size_t OFF_WT   = 0;                               // 4 * 512*512 f16 (WqT,WkT,WvT,WoT)
constexpr size_t OFF_Q16  = OFF_WT  + 4ull * D * D * 2;
constexpr size_t OFF_K16  = OFF_Q16 + (size_t)BS * D * 2;
constexpr size_t OFF_VT   = OFF_K16 + (size_t)BS * D * 2;    // v, transposed: [b*512+n][S]
constexpr size_t OFF_AT   = OFF_VT  + (size_t)BS * D * 2;    // attention output f16 [BS][D]
constexpr size_t OFF_TAB  = OFF_AT  + (size_t)BS * D * 2;    // float [8][1032]
constexpr size_t OFF_COEF = OFF_TAB + 8ull * 1032 * 4;       // float c[8], d[8]; int flag[8]

// ---------------------------------------------------------------------------
// Kernel 1: weight transpose + f32->f16 convert.  WT[n][k] = (f16)W[k][n]
// ---------------------------------------------------------------------------
__global__ __launch_bounds__(256) void wtrans(const float* __restrict__ Wq, const float* __restrict__ Wk,
                                              const float* __restrict__ Wv, const float* __restrict__ Wo,
                                              f16* __restrict__ WT)
{
    __shared__ float tile[64][65];
    const int z = blockIdx.z;
    const float* __restrict__ W = (z == 0) ? Wq : (z == 1) ? Wk : (z == 2) ? Wv : Wo;
    f16* __restrict__ out = WT + (size_t)z * D * D;
    const int k0 = blockIdx.x * 64, n0 = blockIdx.y * 64;
    for (int i = threadIdx.x; i < 4096; i += 256) {
        int r = i >> 6, c = i & 63;
        tile[r][c] = W[(size_t)(k0 + r) * D + n0 + c];
    }
    __syncthreads();
    for (int i = threadIdx.x; i < 4096; i += 256) {
        int nn = i >> 6, kk = i & 63;
        out[(size_t)(n0 + nn) * D + k0 + kk] = (f16)tile[kk][nn];
    }
}

// ---------------------------------------------------------------------------
// Kernel 2: temporal-bias LUT + linearity detection (weights staged in LDS).
// ---------------------------------------------------------------------------
__global__ __launch_bounds__(1024) void build_table(const float* __restrict__ Wt1, const float* __restrict__ bt1,
                                                    const float* __restrict__ Wt2, const float* __restrict__ bt2,
                                                    float* __restrict__ tab, float* __restrict__ coef)
{
    __shared__ float w1s[32], b1s[32], w2s[256], b2s[8];
    __shared__ int dev[8];
    const int t = threadIdx.x;
    if (t < 32)               { w1s[t] = Wt1[t]; b1s[t] = bt1[t]; }
    if (t >= 64 && t < 320)   w2s[t - 64] = Wt2[t - 64];
    if (t >= 320 && t < 328)  b2s[t - 320] = bt2[t - 320];
    if (t < 8) dev[t] = 0;
    __syncthreads();

    float f0[8], f1[8];
#pragma unroll
    for (int hh = 0; hh < 8; ++hh) { f0[hh] = b2s[hh]; f1[hh] = b2s[hh]; }
#pragma unroll 4
    for (int j = 0; j < 32; ++j) {
        float w1 = w1s[j], b1 = b1s[j];
        float h0 = fmaxf(b1, 0.f);
        float h1 = fmaxf(w1 + b1, 0.f);
#pragma unroll
        for (int hh = 0; hh < 8; ++hh) {
            float w2 = w2s[j * 8 + hh];
            f0[hh] += h0 * w2;
            f1[hh] += h1 * w2;
        }
    }

    for (int idx = t; idx <= 1024; idx += 1024) {
        float tdv = (float)idx * (1.0f / 1024.0f);
        float acc[8];
#pragma unroll
        for (int hh = 0; hh < 8; ++hh) acc[hh] = b2s[hh];
#pragma unroll 4
        for (int j = 0; j < 32; ++j) {
            float hv = fmaxf(fmaf(tdv, w1s[j], b1s[j]), 0.f);
#pragma unroll
            for (int hh = 0; hh < 8; ++hh) acc[hh] += hv * w2s[j * 8 + hh];
        }
#pragma unroll
        for (int hh = 0; hh < 8; ++hh) {
            float v = acc[hh] * L2E;
            tab[hh * 1032 + idx] = v;
            float linv = (f0[hh] + tdv * (f1[hh] - f0[hh])) * L2E;
            float dvv = fabsf(v - linv);
            atomicMax(&dev[hh], __float_as_int(dvv));
        }
    }
    __syncthreads();
    if (t == 0) {
#pragma unroll
        for (int hh = 0; hh < 8; ++hh) {
            coef[hh]     = (f1[hh] - f0[hh]) * L2E;
            coef[8 + hh] = f0[hh] * L2E;
            ((int*)coef)[16 + hh] = (__int_as_float(dev[hh]) < 1e-4f) ? 1 : 0;
        }
    }
}

// ---------------------------------------------------------------------------
// Kernel 3: fused q/k/v projection GEMM.  C = A(f32) @ W + b  -> f16.
// 128x64 tile, grid (32,8,3)=768 blocks (3/CU).  4 waves, BK=32, dbuf LDS.
// ---------------------------------------------------------------------------
__global__ __launch_bounds__(256) void proj_gemm(
    const float* __restrict__ Aq, const float* __restrict__ Ak, const float* __restrict__ Av,
    const f16* __restrict__ WT,
    const float* __restrict__ bq, const float* __restrict__ bk, const float* __restrict__ bv,
    f16* __restrict__ q16, f16* __restrict__ k16, f16* __restrict__ vT, float qscale)
{
    __shared__ f16 As[2][128][40];
    __shared__ f16 Bs[2][64][40];

    const int z = blockIdx.z;
    const float* __restrict__ A    = (z == 0) ? Aq : (z == 1) ? Ak : Av;
    const float* __restrict__ bias = (z == 0) ? bq : (z == 1) ? bk : bv;
    const f16* __restrict__ W      = WT + (size_t)z * D * D;
    const float scale = (z == 0) ? qscale : 1.0f;

    const int t = threadIdx.x;
    const int l = t & 63, w = t >> 6;
    const int i16 = l & 15, g = l >> 4;
    const int wm = w >> 1, wn = w & 1;
    const int m0 = blockIdx.x * 128, n0 = blockIdx.y * 64;

    f32x4 acc[4][2] = {};

    float4 ar[4];
    f16x8  br;
    const int arow = t >> 3, ac4 = t & 7;
    const int brow = t >> 2, bc8 = t & 3;

    auto load_stage = [&](int kt) {
        const int k0 = kt * 32;
#pragma unroll
        for (int r = 0; r < 4; ++r)
            ar[r] = *reinterpret_cast<const float4*>(A + (size_t)(m0 + arow + 32 * r) * D + k0 + ac4 * 4);
        br = *reinterpret_cast<const f16x8*>(W + (size_t)(n0 + brow) * D + k0 + bc8 * 8);
    };
    auto write_stage = [&](int buf) {
#pragma unroll
        for (int r = 0; r < 4; ++r) {
            f16x4 hv;
            hv[0] = (f16)ar[r].x; hv[1] = (f16)ar[r].y; hv[2] = (f16)ar[r].z; hv[3] = (f16)ar[r].w;
            *reinterpret_cast<f16x4*>(&As[buf][arow + 32 * r][ac4 * 4]) = hv;
        }
        *reinterpret_cast<f16x8*>(&Bs[buf][brow][bc8 * 8]) = br;
    };

    load_stage(0);
    write_stage(0);
    __syncthreads();

    for (int kt = 0; kt < 16; ++kt) {
        const int cur = kt & 1;
        if (kt < 15) load_stage(kt + 1);

        f16x8 af[4], bf[2];
#pragma unroll
        for (int i = 0; i < 4; ++i)
            af[i] = *reinterpret_cast<const f16x8*>(&As[cur][wm * 64 + i * 16 + i16][g * 8]);
#pragma unroll
        for (int j = 0; j < 2; ++j)
            bf[j] = *reinterpret_cast<const f16x8*>(&Bs[cur][wn * 32 + j * 16 + i16][g * 8]);
#pragma unroll
        for (int i = 0; i < 4; ++i)
#pragma unroll
            for (int j = 0; j < 2; ++j)
                acc[i][j] = __builtin_amdgcn_mfma_f32_16x16x32_f16(af[i], bf[j], acc[i][j], 0, 0, 0);

        if (kt < 15) write_stage(cur ^ 1);
        __syncthreads();
    }

    float bvv[2];
#pragma unroll
    for (int j = 0; j < 2; ++j) bvv[j] = bias[n0 + wn * 32 + j * 16 + i16];

    if (z < 2) {
        f16* __restrict__ out = (z == 0) ? q16 : k16;
#pragma unroll
        for (int i = 0; i < 4; ++i) {
#pragma unroll
            for (int j = 0; j < 2; ++j) {
                const int nn = n0 + wn * 32 + j * 16 + i16;
#pragma unroll
                for (int e = 0; e < 4; ++e) {
                    const int mr = m0 + wm * 64 + i * 16 + g * 4 + e;
                    out[(size_t)mr * D + nn] = (f16)((acc[i][j][e] + bvv[j]) * scale);
                }
            }
        }
    } else {
#pragma unroll
        for (int i = 0; i < 4; ++i) {
            const int mr = m0 + wm * 64 + i * 16 + g * 4;
            const int bb = mr >> 10, jj = mr & 1023;
#pragma unroll
            for (int j = 0; j < 2; ++j) {
                const int nn = n0 + wn * 32 + j * 16 + i16;
                f16x4 hv;
#pragma unroll
                for (int e = 0; e < 4; ++e) hv[e] = (f16)(acc[i][j][e] + bvv[j]);
                *reinterpret_cast<f16x4*>(vT + ((size_t)(bb * D + nn)) * S + jj) = hv;
            }
        }
    }
}

// ---------------------------------------------------------------------------
// Kernel 4: fused flash attention with temporal bias.
// R4: block = 256 thr (4 waves) = one (b,h) x 64 q-rows; each wave 16 rows.
// 512 blocks = 2 blocks/CU = 16 waves/CU (4/SIMD, 2x R2).  K/V staged once
// per block into XOR-swizzled LDS shared by 4 waves -> 2 stage loads + 2 td
// loads per wave-iter (R2:6, R3:10; time tracked #loads x ~270cy latency).
// Swizzle: 16B chunk index ^ (row & 7) for K[32][64], ^ (row & 3) for
// V[64][32] -> every b128 LDS op at the structural bank floor, no padding.
// ---------------------------------------------------------------------------
__global__ __launch_bounds__(256, 2) void attn_kernel(
    const f16* __restrict__ q16, const f16* __restrict__ k16, const f16* __restrict__ vT,
    const float* __restrict__ td, const float* __restrict__ tabg, const float* __restrict__ coef,
    f16* __restrict__ out16)
{
    __shared__ f16 Ks[2][32 * 64];
    __shared__ f16 Vs[2][64 * 32];
    __shared__ f16 Ps[4][16 * 32];

    // bid = qt*32 + h*4 + b: XCD (bid&7) = (4h+b)&7 constant over qt ->
    // all 16 q-tiles of a (b,h) share one XCD's L2 for K/V.
    const int bid = blockIdx.x;
    const int b  = bid & 3;
    const int h  = (bid >> 2) & 7;
    const int qt = bid >> 5;                 // [0,16)

    const int t = threadIdx.x;
    const int w = t >> 6, l = t & 63;
    const int i16 = l & 15, g = l >> 4;
    const int qrow = qt * 64 + w * 16 + i16;

    const float cH = coef[h], dH = coef[8 + h];
    const int lin = ((const int*)coef)[16 + h];
    const float* __restrict__ th = tabg + h * 1032;

    f16x8 qf[2];
#pragma unroll
    for (int kf = 0; kf < 2; ++kf)
        qf[kf] = *reinterpret_cast<const f16x8*>(
            q16 + (size_t)(b * S + qrow) * D + h * 64 + kf * 32 + g * 8);

    float mr = -1e30f, lr = 0.f;
    f32x4 o[4] = {};

    // stage mapping: K tile 32 rows x 8 chunks; V tile 64 rows x 4 chunks
    const int krow = t >> 3, kc8 = t & 7;
    const int vdv  = t >> 2, vj8 = t & 3;
    const int kofs = krow * 64 + ((kc8 ^ (krow & 7)) << 3);
    const int vofs = vdv * 32 + ((vj8 ^ (vdv & 3)) << 3);
    f16x8 sk, sv;

    auto stage_load = [&](int jt) {
        sk = *reinterpret_cast<const f16x8*>(
            k16 + (size_t)(b * S + jt * 32 + krow) * D + h * 64 + kc8 * 8);
        sv = *reinterpret_cast<const f16x8*>(
            vT + (size_t)(b * D + h * 64 + vdv) * S + jt * 32 + vj8 * 8);
    };
    auto stage_write = [&](int buf) {
        *reinterpret_cast<f16x8*>(&Ks[buf][kofs]) = sk;
        *reinterpret_cast<f16x8*>(&Vs[buf][vofs]) = sv;
    };

    // precomputed swizzled LDS read offsets (halves)
    int kro[2][2], vro[4];
#pragma unroll
    for (int fj = 0; fj < 2; ++fj) {
        const int rj = fj * 16 + i16;
        kro[fj][0] = rj * 64 + ((g ^ (i16 & 7)) << 3);
        kro[fj][1] = rj * 64 + (((g + 4) ^ (i16 & 7)) << 3);
    }
#pragma unroll
    for (int fv = 0; fv < 4; ++fv)
        vro[fv] = (fv * 16 + i16) * 32 + ((g ^ (i16 & 3)) << 3);

    const float* __restrict__ tdrow = td + (size_t)(b * S + qrow) * S + g * 4;
    float4 tr0, tr1, tn0, tn1;

    stage_load(0);
    tr0 = *reinterpret_cast<const float4*>(tdrow);
    tr1 = *reinterpret_cast<const float4*>(tdrow + 16);
    stage_write(0);
    __syncthreads();

    for (int jt = 0; jt < 32; ++jt) {
        const int cur = jt & 1;
        if (jt < 31) {
            stage_load(jt + 1);
            tn0 = *reinterpret_cast<const float4*>(tdrow + (jt + 1) * 32);
            tn1 = *reinterpret_cast<const float4*>(tdrow + (jt + 1) * 32 + 16);
        }

        // ---- S^T = K * Q^T ----
        f32x4 s[2];
#pragma unroll
        for (int fj = 0; fj < 2; ++fj) {
            f16x8 ka0 = *reinterpret_cast<const f16x8*>(&Ks[cur][kro[fj][0]]);
            f16x8 ka1 = *reinterpret_cast<const f16x8*>(&Ks[cur][kro[fj][1]]);
            f32x4 zz = {0.f, 0.f, 0.f, 0.f};
            zz = __builtin_amdgcn_mfma_f32_16x16x32_f16(ka0, qf[0], zz, 0, 0, 0);
            s[fj] = __builtin_amdgcn_mfma_f32_16x16x32_f16(ka1, qf[1], zz, 0, 0, 0);
        }

        // ---- bias + online softmax (per-lane q-row i16) ----
        float pvv[2][4];
        float tmax = -1e30f;
#pragma unroll
        for (int fj = 0; fj < 2; ++fj) {
            const float4 t4 = fj ? tr1 : tr0;
            float ta4[4] = {t4.x, t4.y, t4.z, t4.w};
#pragma unroll
            for (int e = 0; e < 4; ++e) {
                float u = ta4[e];
                float vsc;
                if (lin) {
                    vsc = fmaf(u, cH, s[fj][e] + dH);       // td in [0,1): no clamp
                } else {
                    float x = fminf(fmaxf(u, 0.f), 1.f) * 1024.f;
                    int ix = (int)x;
                    ix = (ix > 1023) ? 1023 : ix;
                    float fr = x - (float)ix;
                    float t0v = th[ix], t1v = th[ix + 1];
                    vsc = s[fj][e] + fmaf(fr, t1v - t0v, t0v);
                }
                pvv[fj][e] = vsc;
                tmax = fmaxf(tmax, vsc);
            }
        }
        tmax = fmaxf(tmax, __shfl_xor(tmax, 16));
        tmax = fmaxf(tmax, __shfl_xor(tmax, 32));
        if (__any(tmax > mr)) {                  // T13: skip rescale when max unchanged
            float mnew = fmaxf(mr, tmax);
            float alpha = exp2f(mr - mnew);
            mr = mnew;
            lr *= alpha;
#pragma unroll
            for (int fv = 0; fv < 4; ++fv) o[fv] *= alpha;
        }

        float rsum = 0.f;
        f16x4 pq[2];
#pragma unroll
        for (int fj = 0; fj < 2; ++fj)
#pragma unroll
            for (int e = 0; e < 4; ++e) {
                float p = exp2f(pvv[fj][e] - mr);
                rsum += p;
                pq[fj][e] = (f16)p;
            }
        rsum += __shfl_xor(rsum, 16);
        rsum += __shfl_xor(rsum, 32);
        lr += rsum;

        // P^T relay through per-wave LDS (same wave: no barrier)
        f16* psrow = &Ps[w][i16 * 32];
        *reinterpret_cast<f16x4*>(psrow + g * 4)      = pq[0];
        *reinterpret_cast<f16x4*>(psrow + 16 + g * 4) = pq[1];
        f16x8 pb = *reinterpret_cast<const f16x8*>(psrow + g * 8);

        // ---- out^T += V^T * P^T ----
#pragma unroll
        for (int fv = 0; fv < 4; ++fv) {
            f16x8 va = *reinterpret_cast<const f16x8*>(&Vs[cur][vro[fv]]);
            o[fv] = __builtin_amdgcn_mfma_f32_16x16x32_f16(va, pb, o[fv], 0, 0, 0);
        }

        if (jt < 31) stage_write(cur ^ 1);
        __syncthreads();
        tr0 = tn0; tr1 = tn1;
    }

    // epilogue: out[i][dv] = o^T / lsum
    const float rl = 1.f / lr;
#pragma unroll
    for (int fv = 0; fv < 4; ++fv) {
        f16x4 hv;
#pragma unroll
        for (int e = 0; e < 4; ++e) hv[e] = (f16)(o[fv][e] * rl);
        *reinterpret_cast<f16x4*>(
            out16 + (size_t)(b * S + qrow) * D + h * 64 + fv * 16 + g * 4) = hv;
    }
}

// ---------------------------------------------------------------------------
// Kernel 5: output projection.  out(f32) = attn16(f16) @ Wo + bo
// 64x64 tile, grid (64,8)=512 blocks (2/CU).
// ---------------------------------------------------------------------------
__global__ __launch_bounds__(256) void final_gemm(const f16* __restrict__ A, const f16* __restrict__ WoT,
                                                  const float* __restrict__ bo, float* __restrict__ out)
{
    __shared__ f16 As[2][64][40];
    __shared__ f16 Bs[2][64][40];

    const int t = threadIdx.x;
    const int l = t & 63, w = t >> 6;
    const int i16 = l & 15, g = l >> 4;
    const int wm = w >> 1, wn = w & 1;
    const int m0 = blockIdx.x * 64, n0 = blockIdx.y * 64;

    f32x4 acc[2][2] = {};
    f16x8 ar, br;
    const int srow = t >> 2, sc8 = t & 3;

    auto load_stage = [&](int kt) {
        const int k0 = kt * 32;
        ar = *reinterpret_cast<const f16x8*>(A + (size_t)(m0 + srow) * D + k0 + sc8 * 8);
        br = *reinterpret_cast<const f16x8*>(WoT + (size_t)(n0 + srow) * D + k0 + sc8 * 8);
    };
    auto write_stage = [&](int buf) {
        *reinterpret_cast<f16x8*>(&As[buf][srow][sc8 * 8]) = ar;
        *reinterpret_cast<f16x8*>(&Bs[buf][srow][sc8 * 8]) = br;
    };

    load_stage(0);
    write_stage(0);
    __syncthreads();

    for (int kt = 0; kt < 16; ++kt) {
        const int cur = kt & 1;
        if (kt < 15) load_stage(kt + 1);

        f16x8 af[2], bf[2];
#pragma unroll
        for (int i = 0; i < 2; ++i)
            af[i] = *reinterpret_cast<const f16x8*>(&As[cur][wm * 32 + i * 16 + i16][g * 8]);
#pragma unroll
        for (int j = 0; j < 2; ++j)
            bf[j] = *reinterpret_cast<const f16x8*>(&Bs[cur][wn * 32 + j * 16 + i16][g * 8]);
#pragma unroll
        for (int i = 0; i < 2; ++i)
#pragma unroll
            for (int j = 0; j < 2; ++j)
                acc[i][j] = __builtin_amdgcn_mfma_f32_16x16x32_f16(af[i], bf[j], acc[i][j], 0, 0, 0);

        if (kt < 15) write_stage(cur ^ 1);
        __syncthreads();
    }

    float bvv[2];
#pragma unroll
    for (int j = 0; j < 2; ++j) bvv[j] = bo[n0 + wn * 32 + j * 16 + i16];

#pragma unroll
    for (int i = 0; i < 2; ++i) {
#pragma unroll
        for (int j = 0; j < 2; ++j) {
            const int nn = n0 + wn * 32 + j * 16 + i16;
#pragma unroll
            for (int e = 0; e < 4; ++e) {
                const int mr = m0 + wm * 32 + i * 16 + g * 4 + e;
                out[(size_t)mr * D + nn] = acc[i][j][e] + bvv[j];
            }
        }
    }
}

// ---------------------------------------------------------------------------
extern "C" void kernel_launch(void* const* d_in, const int* in_sizes, int n_in,
                              void* d_out, int out_size, void* d_ws, size_t ws_size,
                              hipStream_t stream)
{
    (void)in_sizes; (void)n_in; (void)out_size; (void)ws_size; // needs ~19 MB of ws

    const float* query = (const float*)d_in[0];
    const float* key_  = (const float*)d_in[1];
    const float* value = (const float*)d_in[2];
    const float* td    = (const float*)d_in[3];
    const float* Wq  = (const float*)d_in[4];  const float* bq  = (const float*)d_in[5];
    const float* Wk  = (const float*)d_in[6];  const float* bk  = (const float*)d_in[7];
    const float* Wv  = (const float*)d_in[8];  const float* bv  = (const float*)d_in[9];
    const float* Wo  = (const float*)d_in[10]; const float* bo  = (const float*)d_in[11];
    const float* Wt1 = (const float*)d_in[12]; const float* bt1 = (const float*)d_in[13];
    const float* Wt2 = (const float*)d_in[14]; const float* bt2 = (const float*)d_in[15];
    float* out = (float*)d_out;

    char* ws = (char*)d_ws;
    f16*   WT   = (f16*)(ws + OFF_WT);
    f16*   q16  = (f16*)(ws + OFF_Q16);
    f16*   k16  = (f16*)(ws + OFF_K16);
    f16*   vT   = (f16*)(ws + OFF_VT);
    f16*   at16 = (f16*)(ws + OFF_AT);
    float* tab  = (float*)(ws + OFF_TAB);
    float* coef = (float*)(ws + OFF_COEF);

    wtrans<<<dim3(8, 8, 4), 256, 0, stream>>>(Wq, Wk, Wv, Wo, WT);
    build_table<<<1, 1024, 0, stream>>>(Wt1, bt1, Wt2, bt2, tab, coef);
    proj_gemm<<<dim3(32, 8, 3), 256, 0, stream>>>(query, key_, value, WT, bq, bk, bv,
                                                  q16, k16, vT, 0.125f * L2E);
    attn_kernel<<<512, 256, 0, stream>>>(q16, k16, vT, td, tab, coef, at16);
    final_gemm<<<dim3(64, 8), 256, 0, stream>>>(at16, WT + 3ull * (size_t)D * D, bo, out);
}